// Round 1
// baseline (70.219 us; speedup 1.0000x reference)
//
#include <hip/hip_runtime.h>

#define BB 4
#define NN 1024
#define MM 1024
#define DD 64
#define TILE 64
#define PAD 68  // padded LDS row stride in floats: 272 B, 16B-aligned, breaks bank aliasing

__global__ __launch_bounds__(256, 4)
void SADSimilarity_38706245272206_kernel(const float* __restrict__ lhs,
                                         const float* __restrict__ rhs,
                                         float* __restrict__ out) {
    __shared__ float lt[TILE * PAD];
    __shared__ float rt[TILE * PAD];

    const int b  = blockIdx.z;
    const int n0 = blockIdx.y * TILE;
    const int m0 = blockIdx.x * TILE;
    const int tid = threadIdx.x;

    const float* lbase = lhs + (size_t)b * NN * DD + (size_t)n0 * DD;
    const float* rbase = rhs + (size_t)b * MM * DD + (size_t)m0 * DD;

    // Stage both tiles (64 rows x 64 d) into LDS. 1024 float4 slots per tile,
    // 256 threads x 4 iterations, fully coalesced along d.
    #pragma unroll
    for (int p = 0; p < 4; ++p) {
        int e   = tid + p * 256;
        int row = e >> 4;
        int q   = (e & 15) << 2;
        float4 lv = *(const float4*)(lbase + row * DD + q);
        float4 rv = *(const float4*)(rbase + row * DD + q);
        *(float4*)(&lt[row * PAD + q]) = lv;
        *(float4*)(&rt[row * PAD + q]) = rv;
    }
    __syncthreads();

    const int tx = tid & 15;   // col group: cols tx + 16*j
    const int ty = tid >> 4;   // row group: rows ty + 16*i

    float acc[4][4];
    #pragma unroll
    for (int i = 0; i < 4; ++i)
        #pragma unroll
        for (int j = 0; j < 4; ++j) acc[i][j] = 0.0f;

    #pragma unroll
    for (int dq = 0; dq < DD / 4; ++dq) {
        float4 l[4], r[4];
        #pragma unroll
        for (int i = 0; i < 4; ++i)
            l[i] = *(const float4*)(&lt[(ty + 16 * i) * PAD + dq * 4]);
        #pragma unroll
        for (int j = 0; j < 4; ++j)
            r[j] = *(const float4*)(&rt[(tx + 16 * j) * PAD + dq * 4]);
        #pragma unroll
        for (int i = 0; i < 4; ++i)
            #pragma unroll
            for (int j = 0; j < 4; ++j) {
                acc[i][j] += fabsf(l[i].x - r[j].x);
                acc[i][j] += fabsf(l[i].y - r[j].y);
                acc[i][j] += fabsf(l[i].z - r[j].z);
                acc[i][j] += fabsf(l[i].w - r[j].w);
            }
    }

    float* obase = out + (size_t)b * NN * MM + (size_t)n0 * MM + m0;
    #pragma unroll
    for (int i = 0; i < 4; ++i) {
        int row = ty + 16 * i;
        #pragma unroll
        for (int j = 0; j < 4; ++j) {
            obase[(size_t)row * MM + tx + 16 * j] = -acc[i][j];
        }
    }
}

extern "C" void kernel_launch(void* const* d_in, const int* in_sizes, int n_in,
                              void* d_out, int out_size, void* d_ws, size_t ws_size,
                              hipStream_t stream) {
    const float* lhs = (const float*)d_in[0];
    const float* rhs = (const float*)d_in[1];
    float* out = (float*)d_out;

    dim3 grid(MM / TILE, NN / TILE, BB);
    dim3 block(256, 1, 1);
    SADSimilarity_38706245272206_kernel<<<grid, block, 0, stream>>>(lhs, rhs, out);
}